// Round 1
// baseline (8495.972 us; speedup 1.0000x reference)
//
#include <hip/hip_runtime.h>

typedef unsigned short ushort_t;
typedef unsigned int uint_t;
typedef __attribute__((ext_vector_type(8))) short bf16x8;
typedef __attribute__((ext_vector_type(4))) float f32x4;

#define B_  16
#define S_  1024
#define D_  1024
#define U_  512
#define GU_ 1536  // 3*U

// ---------- bf16 helpers (RNE) ----------
__device__ __forceinline__ ushort_t f2bf(float f) {
  union { float f; uint_t u; } v; v.f = f;
  uint_t r = v.u + 0x7fffu + ((v.u >> 16) & 1u);
  return (ushort_t)(r >> 16);
}
__device__ __forceinline__ float bf2f(ushort_t b) {
  union { uint_t u; float f; } v; v.u = ((uint_t)b) << 16; return v.f;
}
__device__ __forceinline__ float blo(uint_t d) {
  union { uint_t u; float f; } v; v.u = d << 16; return v.f;
}
__device__ __forceinline__ float bhi(uint_t d) {
  union { uint_t u; float f; } v; v.u = d & 0xffff0000u; return v.f;
}

// ---------- fp32 -> bf16 weight conversion ----------
__global__ void cvt_f32_bf16(const float4* __restrict__ in, ushort4* __restrict__ out, int n4) {
  int i = blockIdx.x * blockDim.x + threadIdx.x;
  int stride = gridDim.x * blockDim.x;
  for (; i < n4; i += stride) {
    float4 f = in[i];
    ushort4 o; o.x = f2bf(f.x); o.y = f2bf(f.y); o.z = f2bf(f.z); o.w = f2bf(f.w);
    out[i] = o;
  }
}

// ---------- LayerNorm: x fp32 [BS, 1024] -> xn bf16 ----------
__global__ __launch_bounds__(256) void ln_kernel(
    const float* __restrict__ x, const float* __restrict__ gamma,
    const float* __restrict__ beta, ushort_t* __restrict__ xn)
{
  int row = blockIdx.x;
  int t = threadIdx.x;
  const float* xr = x + (size_t)row * 1024;
  float4 v = *(const float4*)(xr + t * 4);
  float s = v.x + v.y + v.z + v.w;
  float ss = v.x * v.x + v.y * v.y + v.z * v.z + v.w * v.w;
#pragma unroll
  for (int o = 32; o > 0; o >>= 1) {
    s  += __shfl_down(s, o, 64);
    ss += __shfl_down(ss, o, 64);
  }
  __shared__ float red[2][4];
  __shared__ float mv[2];
  int wv = t >> 6, ln = t & 63;
  if (ln == 0) { red[0][wv] = s; red[1][wv] = ss; }
  __syncthreads();
  if (t == 0) {
    float S1 = red[0][0] + red[0][1] + red[0][2] + red[0][3];
    float S2 = red[1][0] + red[1][1] + red[1][2] + red[1][3];
    float mu = S1 * (1.f / 1024.f);
    float var = S2 * (1.f / 1024.f) - mu * mu;
    mv[0] = mu;
    mv[1] = rsqrtf(var + 1e-5f);
  }
  __syncthreads();
  float mu = mv[0], rs = mv[1];
  float4 gm = *(const float4*)(gamma + t * 4);
  float4 bt = *(const float4*)(beta + t * 4);
  ushort4 o;
  o.x = f2bf((v.x - mu) * rs * gm.x + bt.x);
  o.y = f2bf((v.y - mu) * rs * gm.y + bt.y);
  o.z = f2bf((v.z - mu) * rs * gm.z + bt.z);
  o.w = f2bf((v.w - mu) * rs * gm.w + bt.w);
  *(ushort4*)(xn + (size_t)row * 1024 + t * 4) = o;
}

// ---------- GEMM: C[M,N] = A[M,K](bf16) @ Bw[N,K](bf16)^T + bias (+resid) ----------
// M,N multiples of 128; K multiple of 32. 256 threads, 4 waves in 2x2, each wave 64x64.
template<int RES, int OBF>
__global__ __launch_bounds__(256, 2) void gemm_bt(
    const ushort_t* __restrict__ A, const ushort_t* __restrict__ Bw,
    const float* __restrict__ bias, const float* __restrict__ resid,
    void* __restrict__ Cout, int M, int N, int K)
{
  __shared__ ushort_t As[128][40];  // +8 pad breaks bank aliasing
  __shared__ ushort_t Bs[128][40];
  int bm = blockIdx.x, bn = blockIdx.y;
  int tid = threadIdx.x;
  int wave = tid >> 6, lane = tid & 63;
  int wm = wave >> 1, wn = wave & 1;
  int q = lane >> 4, l16 = lane & 15;
  f32x4 acc[4][4];
#pragma unroll
  for (int i = 0; i < 4; i++)
#pragma unroll
    for (int j = 0; j < 4; j++) acc[i][j] = (f32x4){0.f, 0.f, 0.f, 0.f};
  int r0 = tid >> 2, kc = tid & 3;
  const int nk = K >> 5;
  for (int it = 0; it < nk; ++it) {
#pragma unroll
    for (int h = 0; h < 2; ++h) {
      int r = r0 + h * 64;
      const uint4* pa = (const uint4*)(A + (size_t)(bm * 128 + r) * K + it * 32 + kc * 8);
      *(uint4*)&As[r][kc * 8] = *pa;
      const uint4* pb = (const uint4*)(Bw + (size_t)(bn * 128 + r) * K + it * 32 + kc * 8);
      *(uint4*)&Bs[r][kc * 8] = *pb;
    }
    __syncthreads();
    bf16x8 af[4], bfr[4];
#pragma unroll
    for (int i = 0; i < 4; i++) af[i]  = *(bf16x8*)&As[wm * 64 + i * 16 + l16][q * 8];
#pragma unroll
    for (int j = 0; j < 4; j++) bfr[j] = *(bf16x8*)&Bs[wn * 64 + j * 16 + l16][q * 8];
#pragma unroll
    for (int i = 0; i < 4; i++)
#pragma unroll
      for (int j = 0; j < 4; j++)
        acc[i][j] = __builtin_amdgcn_mfma_f32_16x16x32_bf16(af[i], bfr[j], acc[i][j], 0, 0, 0);
    __syncthreads();
  }
  // epilogue: C/D layout col = lane&15, row = (lane>>4)*4 + reg  [m89-verified]
#pragma unroll
  for (int i = 0; i < 4; i++) {
#pragma unroll
    for (int j = 0; j < 4; j++) {
      int n = bn * 128 + wn * 64 + j * 16 + l16;
      float bv = bias[n];
#pragma unroll
      for (int rr = 0; rr < 4; rr++) {
        int m = bm * 128 + wm * 64 + i * 16 + q * 4 + rr;
        float v = acc[i][j][rr] + bv;
        if (RES) v += resid[(size_t)m * N + n];
        if (OBF) ((ushort_t*)Cout)[(size_t)m * N + n] = f2bf(v);
        else     ((float*)Cout)[(size_t)m * N + n] = v;
      }
    }
  }
}

// ---------- GRU scan ----------
// 256 wgs = 16 batch-groups x 16 members. Member i owns h cols [32i,32i+32) ->
// 96 gh-rows of w_hh as bf16 in dynamic LDS (99 KB => 1 wg/CU => grid of 256 is
// fully co-resident => spin sync cannot deadlock). Cross-wg h exchange via
// agent-scope atomics on a ping-pong h buffer + per-(batch,step) counters.
__global__ __launch_bounds__(192, 1) void scan_kernel(
    const ushort_t* __restrict__ gx, const float* __restrict__ w_hh,
    const float* __restrict__ b_hh, float* __restrict__ hbuf,
    int* __restrict__ cnt, ushort_t* __restrict__ y, float* __restrict__ h_last)
{
  extern __shared__ ushort_t wlds[];   // 192 threads * 264 ushorts (256 data + 16B pad)
  __shared__ float h_sh[512];
  __shared__ float ghs[96];
  __shared__ float gxs[96];

  int blk = blockIdx.x;
  int b = (blk & 7) * 2 + ((blk >> 3) & 1);  // XCD-locality swizzle (heuristic only)
  int i = blk >> 4;
  int c0 = i * 32;
  int t = threadIdx.x;
  int r = t >> 1, half = t & 1;              // thread owns gh-row r, k-half `half`
  int g = r >> 5, cl_r = r & 31;

  { // preload + convert this wg's w_hh slice into LDS (bf16, per-thread contiguous)
    const float* src = w_hh + (size_t)(g * 512 + c0 + cl_r) * 512 + half * 256;
    ushort_t* dst = wlds + (size_t)t * 264;
#pragma unroll 4
    for (int k = 0; k < 256; k += 4) {
      float4 f = *(const float4*)(src + k);
      ushort4 o; o.x = f2bf(f.x); o.y = f2bf(f.y); o.z = f2bf(f.z); o.w = f2bf(f.w);
      *(ushort4*)(dst + k) = o;
    }
  }
  float bhr = 0.f, bhz = 0.f, bhn = 0.f;
  if (t < 32) {
    bhr = b_hh[c0 + t];
    bhz = b_hh[512 + c0 + t];
    bhn = b_hh[1024 + c0 + t];
  }
  __syncthreads();

  for (int step = 0; step < S_; ++step) {
    // stage this step's gx gate slice (independent of the h sync)
    if (t >= 96) {
      int uu = t - 96;
      gxs[uu] = bf2f(gx[((size_t)b * S_ + step) * GU_ + (uu >> 5) * 512 + c0 + (uu & 31)]);
    }
    // stage h_t (published by peers last step; guarded by cnt[step-1])
    const float* hb = hbuf + (size_t)(step & 1) * (B_ * U_) + b * U_;
    if (t < 128) {
#pragma unroll
      for (int j = 0; j < 4; ++j)
        h_sh[j * 128 + t] = __hip_atomic_load(hb + j * 128 + t, __ATOMIC_RELAXED,
                                              __HIP_MEMORY_SCOPE_AGENT);
    }
    __syncthreads();

    // GEMV: 256 MACs/thread from register-unpacked bf16 LDS weights
    float acc = 0.f;
    const ushort_t* wp = wlds + (size_t)t * 264;
    const float* hp = h_sh + half * 256;
#pragma unroll 8
    for (int k = 0; k < 256; k += 8) {
      uint4 wv = *(const uint4*)(wp + k);
      float4 h0 = *(const float4*)(hp + k);
      float4 h1 = *(const float4*)(hp + k + 4);
      acc += blo(wv.x) * h0.x + bhi(wv.x) * h0.y
           + blo(wv.y) * h0.z + bhi(wv.y) * h0.w
           + blo(wv.z) * h1.x + bhi(wv.z) * h1.y
           + blo(wv.w) * h1.z + bhi(wv.w) * h1.w;
    }
    acc += __shfl_xor(acc, 1, 64);    // t and t^1 share row r
    if (half == 0) ghs[r] = acc;
    __syncthreads();

    if (t < 32) {
      float xr = gxs[t], xz = gxs[32 + t], xnn = gxs[64 + t];
      float hr = ghs[t] + bhr;
      float hz = ghs[32 + t] + bhz;
      float hn = ghs[64 + t] + bhn;
      float rg = 1.f / (1.f + __expf(-(xr + hr)));
      float zg = 1.f / (1.f + __expf(-(xz + hz)));
      float na = xnn + rg * hn;
      float e = __expf(-2.f * na);
      float ng = (1.f - e) / (1.f + e);
      float hold = h_sh[c0 + t];
      float hv = (1.f - zg) * ng + zg * hold;
      float* hw = hbuf + (size_t)((step + 1) & 1) * (B_ * U_) + b * U_ + c0 + t;
      __hip_atomic_store(hw, hv, __ATOMIC_RELAXED, __HIP_MEMORY_SCOPE_AGENT);
      y[((size_t)b * S_ + step) * U_ + c0 + t] = f2bf(hv);
      if (step == S_ - 1) h_last[b * U_ + c0 + t] = hv;
    }
    __syncthreads();  // drains vmcnt: h/y stores complete before publish
    if (t == 0) {
      __hip_atomic_fetch_add(&cnt[b * S_ + step], 1, __ATOMIC_RELEASE,
                             __HIP_MEMORY_SCOPE_AGENT);
      while (__hip_atomic_load(&cnt[b * S_ + step], __ATOMIC_ACQUIRE,
                               __HIP_MEMORY_SCOPE_AGENT) < 16) { }
    }
    __syncthreads();
  }
}

extern "C" void kernel_launch(void* const* d_in, const int* in_sizes, int n_in,
                              void* d_out, int out_size, void* d_ws, size_t ws_size,
                              hipStream_t stream) {
  const float* x     = (const float*)d_in[0];
  const float* ln_g  = (const float*)d_in[1];
  const float* ln_b  = (const float*)d_in[2];
  const float* w_in  = (const float*)d_in[3];
  const float* b_in  = (const float*)d_in[4];
  const float* w_ih  = (const float*)d_in[5];
  const float* w_hh  = (const float*)d_in[6];
  const float* b_ih  = (const float*)d_in[7];
  const float* b_hh  = (const float*)d_in[8];
  const float* w_out = (const float*)d_in[9];
  const float* b_out = (const float*)d_in[10];

  float* out = (float*)d_out;                       // [B,S,D] fp32
  float* h_last = out + (size_t)B_ * S_ * D_;       // [B,U] fp32

  char* ws = (char*)d_ws;
  size_t off = 0;
  ushort_t* xn   = (ushort_t*)(ws + off); off += (size_t)B_ * S_ * D_ * 2;   // 32 MB
  ushort_t* u    = (ushort_t*)(ws + off); off += (size_t)B_ * S_ * U_ * 2;   // 16 MB
  ushort_t* gx   = (ushort_t*)(ws + off); off += (size_t)B_ * S_ * GU_ * 2;  // 48 MB
  ushort_t* y    = (ushort_t*)(ws + off); off += (size_t)B_ * S_ * U_ * 2;   // 16 MB
  ushort_t* winb = (ushort_t*)(ws + off); off += (size_t)U_ * D_ * 2;
  ushort_t* wihb = (ushort_t*)(ws + off); off += (size_t)GU_ * U_ * 2;
  ushort_t* woub = (ushort_t*)(ws + off); off += (size_t)D_ * U_ * 2;
  float* hbuf    = (float*)(ws + off);    off += (size_t)2 * B_ * U_ * 4;    // 64 KB
  int* cnt       = (int*)(ws + off);      off += (size_t)B_ * S_ * 4;        // 64 KB

  // zero ping-pong h buffer + arrival counters (contiguous)
  hipMemsetAsync(hbuf, 0, (size_t)2 * B_ * U_ * 4 + (size_t)B_ * S_ * 4, stream);

  cvt_f32_bf16<<<512, 256, 0, stream>>>((const float4*)w_in,  (ushort4*)winb, U_ * D_ / 4);
  cvt_f32_bf16<<<512, 256, 0, stream>>>((const float4*)w_ih,  (ushort4*)wihb, GU_ * U_ / 4);
  cvt_f32_bf16<<<512, 256, 0, stream>>>((const float4*)w_out, (ushort4*)woub, D_ * U_ / 4);

  ln_kernel<<<B_ * S_, 256, 0, stream>>>(x, ln_g, ln_b, xn);

  // u = xn @ w_in^T + b_in  (M=16384, N=512, K=1024)
  gemm_bt<0, 1><<<dim3(B_ * S_ / 128, U_ / 128), 256, 0, stream>>>(
      xn, winb, b_in, nullptr, u, B_ * S_, U_, D_);
  // gx = u @ w_ih^T + b_ih  (M=16384, N=1536, K=512)
  gemm_bt<0, 1><<<dim3(B_ * S_ / 128, GU_ / 128), 256, 0, stream>>>(
      u, wihb, b_ih, nullptr, gx, B_ * S_, GU_, U_);

  // sequential GRU over S
  (void)hipFuncSetAttribute(reinterpret_cast<const void*>(scan_kernel),
                            hipFuncAttributeMaxDynamicSharedMemorySize, 192 * 264 * 2);
  scan_kernel<<<256, 192, 192 * 264 * 2, stream>>>(gx, w_hh, b_hh, hbuf, cnt, y, h_last);

  // out = x + y @ w_out^T + b_out  (M=16384, N=1024, K=512)
  gemm_bt<1, 0><<<dim3(B_ * S_ / 128, D_ / 128), 256, 0, stream>>>(
      y, woub, b_out, x, out, B_ * S_, D_, U_);
}

// Round 2
// 4151.397 us; speedup vs baseline: 2.0465x; 2.0465x over previous
//
#include <hip/hip_runtime.h>

typedef unsigned short ushort_t;
typedef unsigned int uint_t;
typedef __attribute__((ext_vector_type(8))) short bf16x8;
typedef __attribute__((ext_vector_type(4))) float f32x4;

#define B_  16
#define S_  1024
#define D_  1024
#define U_  512
#define GU_ 1536  // 3*U

// ---------- bf16 helpers (RNE) ----------
__device__ __forceinline__ ushort_t f2bf(float f) {
  union { float f; uint_t u; } v; v.f = f;
  uint_t r = v.u + 0x7fffu + ((v.u >> 16) & 1u);
  return (ushort_t)(r >> 16);
}
__device__ __forceinline__ float bf2f(ushort_t b) {
  union { uint_t u; float f; } v; v.u = ((uint_t)b) << 16; return v.f;
}

// ---------- fp32 -> bf16 weight conversion ----------
__global__ void cvt_f32_bf16(const float4* __restrict__ in, ushort4* __restrict__ out, int n4) {
  int i = blockIdx.x * blockDim.x + threadIdx.x;
  int stride = gridDim.x * blockDim.x;
  for (; i < n4; i += stride) {
    float4 f = in[i];
    ushort4 o; o.x = f2bf(f.x); o.y = f2bf(f.y); o.z = f2bf(f.z); o.w = f2bf(f.w);
    out[i] = o;
  }
}

// ---------- LayerNorm: x fp32 [BS, 1024] -> xn bf16 ----------
__global__ __launch_bounds__(256) void ln_kernel(
    const float* __restrict__ x, const float* __restrict__ gamma,
    const float* __restrict__ beta, ushort_t* __restrict__ xn)
{
  int row = blockIdx.x;
  int t = threadIdx.x;
  const float* xr = x + (size_t)row * 1024;
  float4 v = *(const float4*)(xr + t * 4);
  float s = v.x + v.y + v.z + v.w;
  float ss = v.x * v.x + v.y * v.y + v.z * v.z + v.w * v.w;
#pragma unroll
  for (int o = 32; o > 0; o >>= 1) {
    s  += __shfl_down(s, o, 64);
    ss += __shfl_down(ss, o, 64);
  }
  __shared__ float red[2][4];
  __shared__ float mv[2];
  int wv = t >> 6, ln = t & 63;
  if (ln == 0) { red[0][wv] = s; red[1][wv] = ss; }
  __syncthreads();
  if (t == 0) {
    float S1 = red[0][0] + red[0][1] + red[0][2] + red[0][3];
    float S2 = red[1][0] + red[1][1] + red[1][2] + red[1][3];
    float mu = S1 * (1.f / 1024.f);
    float var = S2 * (1.f / 1024.f) - mu * mu;
    mv[0] = mu;
    mv[1] = rsqrtf(var + 1e-5f);
  }
  __syncthreads();
  float mu = mv[0], rs = mv[1];
  float4 gm = *(const float4*)(gamma + t * 4);
  float4 bt = *(const float4*)(beta + t * 4);
  ushort4 o;
  o.x = f2bf((v.x - mu) * rs * gm.x + bt.x);
  o.y = f2bf((v.y - mu) * rs * gm.y + bt.y);
  o.z = f2bf((v.z - mu) * rs * gm.z + bt.z);
  o.w = f2bf((v.w - mu) * rs * gm.w + bt.w);
  *(ushort4*)(xn + (size_t)row * 1024 + t * 4) = o;
}

// ---------- GEMM: C[M,N] = A[M,K](bf16) @ Bw[N,K](bf16)^T + bias (+resid) ----------
template<int RES, int OBF>
__global__ __launch_bounds__(256, 2) void gemm_bt(
    const ushort_t* __restrict__ A, const ushort_t* __restrict__ Bw,
    const float* __restrict__ bias, const float* __restrict__ resid,
    void* __restrict__ Cout, int M, int N, int K)
{
  __shared__ ushort_t As[128][40];
  __shared__ ushort_t Bs[128][40];
  int bm = blockIdx.x, bn = blockIdx.y;
  int tid = threadIdx.x;
  int wave = tid >> 6, lane = tid & 63;
  int wm = wave >> 1, wn = wave & 1;
  int q = lane >> 4, l16 = lane & 15;
  f32x4 acc[4][4];
#pragma unroll
  for (int i = 0; i < 4; i++)
#pragma unroll
    for (int j = 0; j < 4; j++) acc[i][j] = (f32x4){0.f, 0.f, 0.f, 0.f};
  int r0 = tid >> 2, kc = tid & 3;
  const int nk = K >> 5;
  for (int it = 0; it < nk; ++it) {
#pragma unroll
    for (int h = 0; h < 2; ++h) {
      int r = r0 + h * 64;
      const uint4* pa = (const uint4*)(A + (size_t)(bm * 128 + r) * K + it * 32 + kc * 8);
      *(uint4*)&As[r][kc * 8] = *pa;
      const uint4* pb = (const uint4*)(Bw + (size_t)(bn * 128 + r) * K + it * 32 + kc * 8);
      *(uint4*)&Bs[r][kc * 8] = *pb;
    }
    __syncthreads();
    bf16x8 af[4], bfr[4];
#pragma unroll
    for (int i = 0; i < 4; i++) af[i]  = *(bf16x8*)&As[wm * 64 + i * 16 + l16][q * 8];
#pragma unroll
    for (int j = 0; j < 4; j++) bfr[j] = *(bf16x8*)&Bs[wn * 64 + j * 16 + l16][q * 8];
#pragma unroll
    for (int i = 0; i < 4; i++)
#pragma unroll
      for (int j = 0; j < 4; j++)
        acc[i][j] = __builtin_amdgcn_mfma_f32_16x16x32_bf16(af[i], bfr[j], acc[i][j], 0, 0, 0);
    __syncthreads();
  }
#pragma unroll
  for (int i = 0; i < 4; i++) {
#pragma unroll
    for (int j = 0; j < 4; j++) {
      int n = bn * 128 + wn * 64 + j * 16 + l16;
      float bv = bias[n];
#pragma unroll
      for (int rr = 0; rr < 4; rr++) {
        int m = bm * 128 + wm * 64 + i * 16 + q * 4 + rr;
        float v = acc[i][j][rr] + bv;
        if (RES) v += resid[(size_t)m * N + n];
        if (OBF) ((ushort_t*)Cout)[(size_t)m * N + n] = f2bf(v);
        else     ((float*)Cout)[(size_t)m * N + n] = v;
      }
    }
  }
}

// ---------- GRU scan (batched MFMA, 16 wgs) ----------
// wg m owns h-cols [32m, 32m+32) for ALL 16 batches. Per step:
//   gh[b][96] = h_t[b][512](bf16) @ w_slice[96,512]^T  via 96 MFMAs on 2 waves.
// h exchange: per-step mailbox hbuf[step][b][colpair] (bypass dword atomics,
// fresh addresses => no ABA, no stale-cache hazard) + one flag line per step.
// Wave w handles hcols w*16+l16; its 3 acc tiles are the r,z,n gates for
// exactly those cols => gate math fully in-register. h state fp32 in VGPRs.
__global__ __launch_bounds__(128, 1) void scan_kernel(
    const ushort_t* __restrict__ gx, const float* __restrict__ w_hh,
    const float* __restrict__ b_hh, uint_t* __restrict__ hbuf,
    uint_t* __restrict__ flags, ushort_t* __restrict__ y, float* __restrict__ h_last)
{
  extern __shared__ char smem[];
  ushort_t* wlds = (ushort_t*)smem;              // 96 KB: [cc=nt*16+ks][lane][8] B-frag order
  char* hshb = smem + 96 * 1024;                 // 16 KB: [b][512] bf16, 16B-chunk XOR swizzle
  ushort_t* gxs = (ushort_t*)(smem + 112 * 1024);// 6 KB: [2][16][3][32] bf16

  const int m = blockIdx.x;
  const int c0 = m * 32;
  const int t = threadIdx.x;
  const int wv = t >> 6, lane = t & 63, q = lane >> 4, l16 = lane & 15;

  // ---- init: stage w_hh slice into LDS in exact B-fragment read order ----
  for (int idx = t; idx < 96 * 64; idx += 128) {
    int cc = idx >> 6, ln = idx & 63;
    int nt = cc >> 4, ks = cc & 15;
    int g = nt >> 1, ccl = ((nt & 1) << 4) + (ln & 15);
    int k0 = (ks << 5) + ((ln >> 4) << 3);
    const float* src = w_hh + (size_t)(g * 512 + c0 + ccl) * 512 + k0;
    float4 f0 = *(const float4*)src;
    float4 f1 = *(const float4*)(src + 4);
    uint4 pk;
    pk.x = (uint_t)f2bf(f0.x) | ((uint_t)f2bf(f0.y) << 16);
    pk.y = (uint_t)f2bf(f0.z) | ((uint_t)f2bf(f0.w) << 16);
    pk.z = (uint_t)f2bf(f1.x) | ((uint_t)f2bf(f1.y) << 16);
    pk.w = (uint_t)f2bf(f1.z) | ((uint_t)f2bf(f1.w) << 16);
    *(uint4*)(wlds + (size_t)cc * 512 + ln * 8) = pk;
  }

  const int cl = (wv << 4) + l16;        // owned hcol within slice, 0..31
  const float bhr = b_hh[c0 + cl];
  const float bhz = b_hh[512 + c0 + cl];
  const float bhn = b_hh[1024 + c0 + cl];
  float hcur[4] = {0.f, 0.f, 0.f, 0.f};

  // gx prefetch for step 0 into gxs buf0
  const int pb = t >> 3, pj = t & 7;
  const size_t gxrow = (size_t)pb * S_ * GU_;
  uint2 g3[3];
#pragma unroll
  for (int g = 0; g < 3; ++g)
    g3[g] = *(const uint2*)(gx + gxrow + g * 512 + c0 + pj * 4);
#pragma unroll
  for (int g = 0; g < 3; ++g)
    *(uint2*)(gxs + (pb * 3 + g) * 32 + pj * 4) = g3[g];
  __syncthreads();

  // cache ks=8..15 w-fragments in VGPRs (halves steady-state LDS traffic)
  bf16x8 wreg[3][8];
#pragma unroll
  for (int gi = 0; gi < 3; ++gi)
#pragma unroll
    for (int k8 = 0; k8 < 8; ++k8) {
      int cc = ((gi * 2 + wv) << 4) + 8 + k8;
      wreg[gi][k8] = *(bf16x8*)(wlds + (size_t)cc * 512 + lane * 8);
    }

  for (int step = 0; step < S_; ++step) {
    // ---- wait for all 16 members' step-1 publishes ----
    if (step > 0) {
      if (t < 16) {
        uint_t* fp = flags + (size_t)(step - 1) * 16 + t;
        while (__hip_atomic_load(fp, __ATOMIC_RELAXED, __HIP_MEMORY_SCOPE_AGENT) == 0u) {}
      }
    }
    __syncthreads();
    // ---- stage h_{t} (bf16) into swizzled hsh ----
    if (step > 0) {
      uint_t* hb = hbuf + (size_t)(step - 1) * 4096;
#pragma unroll
      for (int blk = 0; blk < 4; ++blk) {
        uint_t vv[8];
#pragma unroll
        for (int u2 = 0; u2 < 8; ++u2) {
          int d = (blk * 8 + u2) * 128 + t;
          vv[u2] = __hip_atomic_load(hb + d, __ATOMIC_RELAXED, __HIP_MEMORY_SCOPE_AGENT);
        }
#pragma unroll
        for (int u2 = 0; u2 < 8; ++u2) {
          int d = (blk * 8 + u2) * 128 + t;
          int b = d >> 8, col0 = (d & 255) << 1;
          int chunk = col0 >> 3;
          *(uint_t*)(hshb + b * 1024 + ((chunk ^ (b & 7)) << 4) + ((col0 & 7) << 1)) = vv[u2];
        }
      }
    } else {
      for (int it = 0; it < 32; ++it)
        *(uint_t*)(hshb + (it * 128 + t) * 4) = 0u;
    }
    __syncthreads();

    // ---- MFMA: gh[b=row][ghrow=col] for this wave's 3 gate tiles ----
    f32x4 acc[3] = {{0.f,0.f,0.f,0.f},{0.f,0.f,0.f,0.f},{0.f,0.f,0.f,0.f}};
#pragma unroll
    for (int ks = 0; ks < 16; ++ks) {
      bf16x8 hf = *(bf16x8*)(hshb + l16 * 1024 + ((((ks << 2) + q) ^ (l16 & 7)) << 4));
#pragma unroll
      for (int gi = 0; gi < 3; ++gi) {
        bf16x8 wf;
        if (ks < 8) {
          int cc = ((gi * 2 + wv) << 4) + ks;
          wf = *(bf16x8*)(wlds + (size_t)cc * 512 + lane * 8);
        } else {
          wf = wreg[gi][ks - 8];
        }
        acc[gi] = __builtin_amdgcn_mfma_f32_16x16x32_bf16(hf, wf, acc[gi], 0, 0, 0);
      }
    }

    // ---- prefetch next step's gx while MFMA results settle ----
    int sp1 = (step + 1 < S_) ? step + 1 : step;
#pragma unroll
    for (int g = 0; g < 3; ++g)
      g3[g] = *(const uint2*)(gx + gxrow + (size_t)sp1 * GU_ + g * 512 + c0 + pj * 4);
    int pbuf = ((step + 1) & 1) * 1536;
#pragma unroll
    for (int g = 0; g < 3; ++g)
      *(uint2*)(gxs + pbuf + (pb * 3 + g) * 32 + pj * 4) = g3[g];
    __syncthreads();

    // ---- gates: fully in-register (row=batch=q*4+r, col=hcol=cl) ----
    const ushort_t* gxb = gxs + (step & 1) * 1536;
    float hnew[4];
#pragma unroll
    for (int r = 0; r < 4; ++r) {
      int b = (q << 2) + r;
      float xr  = bf2f(gxb[(b * 3 + 0) * 32 + cl]);
      float xz  = bf2f(gxb[(b * 3 + 1) * 32 + cl]);
      float xnn = bf2f(gxb[(b * 3 + 2) * 32 + cl]);
      float rr = 1.f / (1.f + __expf(-(xr + acc[0][r] + bhr)));
      float zz = 1.f / (1.f + __expf(-(xz + acc[1][r] + bhz)));
      float na = xnn + rr * (acc[2][r] + bhn);
      float e = __expf(-2.f * na);
      float ng = (1.f - e) / (1.f + e);
      hnew[r] = (1.f - zz) * ng + zz * hcur[r];
      hcur[r] = hnew[r];
    }
    // ---- publish: pack col pairs via shfl, even lanes store dwords ----
    uint_t mycol = c0 + cl;
#pragma unroll
    for (int r = 0; r < 4; ++r) {
      uint_t hb16 = f2bf(hnew[r]);
      uint_t other = (uint_t)__shfl_xor((int)hb16, 1, 64);
      if ((lane & 1) == 0) {
        uint_t dw = hb16 | (other << 16);
        int b = (q << 2) + r;
        __hip_atomic_store(hbuf + (size_t)step * 4096 + b * 256 + (mycol >> 1), dw,
                           __ATOMIC_RELAXED, __HIP_MEMORY_SCOPE_AGENT);
        *(uint_t*)(y + ((size_t)b * S_ + step) * U_ + mycol) = dw;
      }
    }
    if (step == S_ - 1) {
#pragma unroll
      for (int r = 0; r < 4; ++r)
        h_last[((q << 2) + r) * 512 + mycol] = hnew[r];
    }
    __syncthreads();   // emits s_waitcnt vmcnt(0): all publishes drained
    if (t == 0)
      __hip_atomic_store(flags + (size_t)step * 16 + m, 1u,
                         __ATOMIC_RELAXED, __HIP_MEMORY_SCOPE_AGENT);
  }
}

extern "C" void kernel_launch(void* const* d_in, const int* in_sizes, int n_in,
                              void* d_out, int out_size, void* d_ws, size_t ws_size,
                              hipStream_t stream) {
  const float* x     = (const float*)d_in[0];
  const float* ln_g  = (const float*)d_in[1];
  const float* ln_b  = (const float*)d_in[2];
  const float* w_in  = (const float*)d_in[3];
  const float* b_in  = (const float*)d_in[4];
  const float* w_ih  = (const float*)d_in[5];
  const float* w_hh  = (const float*)d_in[6];
  const float* b_ih  = (const float*)d_in[7];
  const float* b_hh  = (const float*)d_in[8];
  const float* w_out = (const float*)d_in[9];
  const float* b_out = (const float*)d_in[10];

  float* out = (float*)d_out;                       // [B,S,D] fp32
  float* h_last = out + (size_t)B_ * S_ * D_;       // [B,U] fp32

  char* ws = (char*)d_ws;
  size_t off = 0;
  ushort_t* xn   = (ushort_t*)(ws + off); off += (size_t)B_ * S_ * D_ * 2;   // 32 MB
  ushort_t* u    = (ushort_t*)(ws + off); off += (size_t)B_ * S_ * U_ * 2;   // 16 MB
  ushort_t* gx   = (ushort_t*)(ws + off); off += (size_t)B_ * S_ * GU_ * 2;  // 48 MB
  ushort_t* y    = (ushort_t*)(ws + off); off += (size_t)B_ * S_ * U_ * 2;   // 16 MB
  ushort_t* winb = (ushort_t*)(ws + off); off += (size_t)U_ * D_ * 2;
  ushort_t* wihb = (ushort_t*)(ws + off); off += (size_t)GU_ * U_ * 2;
  ushort_t* woub = (ushort_t*)(ws + off); off += (size_t)D_ * U_ * 2;
  uint_t* flags  = (uint_t*)(ws + off);   off += (size_t)S_ * 16 * 4;        // 64 KB
  // per-step h mailboxes (16 MB) alias the xn buffer: xn is dead after GEMM1,
  // scan runs strictly after GEMM1 on the same stream.
  uint_t* hbuf = (uint_t*)xn;

  hipMemsetAsync(flags, 0, (size_t)S_ * 16 * 4, stream);

  cvt_f32_bf16<<<512, 256, 0, stream>>>((const float4*)w_in,  (ushort4*)winb, U_ * D_ / 4);
  cvt_f32_bf16<<<512, 256, 0, stream>>>((const float4*)w_ih,  (ushort4*)wihb, GU_ * U_ / 4);
  cvt_f32_bf16<<<512, 256, 0, stream>>>((const float4*)w_out, (ushort4*)woub, D_ * U_ / 4);

  ln_kernel<<<B_ * S_, 256, 0, stream>>>(x, ln_g, ln_b, xn);

  // u = xn @ w_in^T + b_in  (M=16384, N=512, K=1024)
  gemm_bt<0, 1><<<dim3(B_ * S_ / 128, U_ / 128), 256, 0, stream>>>(
      xn, winb, b_in, nullptr, u, B_ * S_, U_, D_);
  // gx = u @ w_ih^T + b_ih  (M=16384, N=1536, K=512)
  gemm_bt<0, 1><<<dim3(B_ * S_ / 128, GU_ / 128), 256, 0, stream>>>(
      u, wihb, b_ih, nullptr, gx, B_ * S_, GU_, U_);

  // sequential GRU over S: 16 wgs, 120832 B dynamic LDS each
  (void)hipFuncSetAttribute(reinterpret_cast<const void*>(scan_kernel),
                            hipFuncAttributeMaxDynamicSharedMemorySize, 120832);
  scan_kernel<<<16, 128, 120832, stream>>>(gx, w_hh, b_hh, hbuf, flags, y, h_last);

  // out = x + y @ w_out^T + b_out  (M=16384, N=1024, K=512)
  gemm_bt<1, 0><<<dim3(B_ * S_ / 128, D_ / 128), 256, 0, stream>>>(
      y, woub, b_out, x, out, B_ * S_, D_, U_);
}

// Round 3
// 4086.075 us; speedup vs baseline: 2.0793x; 1.0160x over previous
//
#include <hip/hip_runtime.h>

typedef unsigned short ushort_t;
typedef unsigned int uint_t;
typedef __attribute__((ext_vector_type(8))) short bf16x8;
typedef __attribute__((ext_vector_type(4))) float f32x4;

#define B_  16
#define S_  1024
#define D_  1024
#define U_  512
#define GU_ 1536  // 3*U

// ---------- bf16 helpers (RNE) ----------
__device__ __forceinline__ ushort_t f2bf(float f) {
  union { float f; uint_t u; } v; v.f = f;
  uint_t r = v.u + 0x7fffu + ((v.u >> 16) & 1u);
  return (ushort_t)(r >> 16);
}
__device__ __forceinline__ float bf2f(ushort_t b) {
  union { uint_t u; float f; } v; v.u = ((uint_t)b) << 16; return v.f;
}

// ---------- fp32 -> bf16 weight conversion ----------
__global__ void cvt_f32_bf16(const float4* __restrict__ in, ushort4* __restrict__ out, int n4) {
  int i = blockIdx.x * blockDim.x + threadIdx.x;
  int stride = gridDim.x * blockDim.x;
  for (; i < n4; i += stride) {
    float4 f = in[i];
    ushort4 o; o.x = f2bf(f.x); o.y = f2bf(f.y); o.z = f2bf(f.z); o.w = f2bf(f.w);
    out[i] = o;
  }
}

// ---------- LayerNorm: x fp32 [BS, 1024] -> xn bf16 ----------
__global__ __launch_bounds__(256) void ln_kernel(
    const float* __restrict__ x, const float* __restrict__ gamma,
    const float* __restrict__ beta, ushort_t* __restrict__ xn)
{
  int row = blockIdx.x;
  int t = threadIdx.x;
  const float* xr = x + (size_t)row * 1024;
  float4 v = *(const float4*)(xr + t * 4);
  float s = v.x + v.y + v.z + v.w;
  float ss = v.x * v.x + v.y * v.y + v.z * v.z + v.w * v.w;
#pragma unroll
  for (int o = 32; o > 0; o >>= 1) {
    s  += __shfl_down(s, o, 64);
    ss += __shfl_down(ss, o, 64);
  }
  __shared__ float red[2][4];
  __shared__ float mv[2];
  int wv = t >> 6, ln = t & 63;
  if (ln == 0) { red[0][wv] = s; red[1][wv] = ss; }
  __syncthreads();
  if (t == 0) {
    float S1 = red[0][0] + red[0][1] + red[0][2] + red[0][3];
    float S2 = red[1][0] + red[1][1] + red[1][2] + red[1][3];
    float mu = S1 * (1.f / 1024.f);
    float var = S2 * (1.f / 1024.f) - mu * mu;
    mv[0] = mu;
    mv[1] = rsqrtf(var + 1e-5f);
  }
  __syncthreads();
  float mu = mv[0], rs = mv[1];
  float4 gm = *(const float4*)(gamma + t * 4);
  float4 bt = *(const float4*)(beta + t * 4);
  ushort4 o;
  o.x = f2bf((v.x - mu) * rs * gm.x + bt.x);
  o.y = f2bf((v.y - mu) * rs * gm.y + bt.y);
  o.z = f2bf((v.z - mu) * rs * gm.z + bt.z);
  o.w = f2bf((v.w - mu) * rs * gm.w + bt.w);
  *(ushort4*)(xn + (size_t)row * 1024 + t * 4) = o;
}

// ---------- GEMM: C[M,N] = A[M,K](bf16) @ Bw[N,K](bf16)^T + bias (+resid) ----------
template<int RES, int OBF>
__global__ __launch_bounds__(256, 2) void gemm_bt(
    const ushort_t* __restrict__ A, const ushort_t* __restrict__ Bw,
    const float* __restrict__ bias, const float* __restrict__ resid,
    void* __restrict__ Cout, int M, int N, int K)
{
  __shared__ ushort_t As[128][40];
  __shared__ ushort_t Bs[128][40];
  int bm = blockIdx.x, bn = blockIdx.y;
  int tid = threadIdx.x;
  int wave = tid >> 6, lane = tid & 63;
  int wm = wave >> 1, wn = wave & 1;
  int q = lane >> 4, l16 = lane & 15;
  f32x4 acc[4][4];
#pragma unroll
  for (int i = 0; i < 4; i++)
#pragma unroll
    for (int j = 0; j < 4; j++) acc[i][j] = (f32x4){0.f, 0.f, 0.f, 0.f};
  int r0 = tid >> 2, kc = tid & 3;
  const int nk = K >> 5;
  for (int it = 0; it < nk; ++it) {
#pragma unroll
    for (int h = 0; h < 2; ++h) {
      int r = r0 + h * 64;
      const uint4* pa = (const uint4*)(A + (size_t)(bm * 128 + r) * K + it * 32 + kc * 8);
      *(uint4*)&As[r][kc * 8] = *pa;
      const uint4* pb = (const uint4*)(Bw + (size_t)(bn * 128 + r) * K + it * 32 + kc * 8);
      *(uint4*)&Bs[r][kc * 8] = *pb;
    }
    __syncthreads();
    bf16x8 af[4], bfr[4];
#pragma unroll
    for (int i = 0; i < 4; i++) af[i]  = *(bf16x8*)&As[wm * 64 + i * 16 + l16][q * 8];
#pragma unroll
    for (int j = 0; j < 4; j++) bfr[j] = *(bf16x8*)&Bs[wn * 64 + j * 16 + l16][q * 8];
#pragma unroll
    for (int i = 0; i < 4; i++)
#pragma unroll
      for (int j = 0; j < 4; j++)
        acc[i][j] = __builtin_amdgcn_mfma_f32_16x16x32_bf16(af[i], bfr[j], acc[i][j], 0, 0, 0);
    __syncthreads();
  }
#pragma unroll
  for (int i = 0; i < 4; i++) {
#pragma unroll
    for (int j = 0; j < 4; j++) {
      int n = bn * 128 + wn * 64 + j * 16 + l16;
      float bv = bias[n];
#pragma unroll
      for (int rr = 0; rr < 4; rr++) {
        int m = bm * 128 + wm * 64 + i * 16 + q * 4 + rr;
        float v = acc[i][j][rr] + bv;
        if (RES) v += resid[(size_t)m * N + n];
        if (OBF) ((ushort_t*)Cout)[(size_t)m * N + n] = f2bf(v);
        else     ((float*)Cout)[(size_t)m * N + n] = v;
      }
    }
  }
}

// ---------- GRU scan (16 wgs, tagged mailbox, w_hh in VGPRs) ----------
// wg m owns h-cols [32m,32m+32) for all 16 batches. Mailbox entry per
// (step,b,col): dword = bf16(h)<<16 | (step+1). No flags, no ordering needed:
// the tag is the ready bit; stale/poisoned reads fail the tag check and are
// re-polled with a fresh bypass burst. w_hh fragments live entirely in VGPRs
// (48 x bf16x8 = 192 VGPRs; 1 wg/CU so 512 VGPR/wave budget).
__global__ __launch_bounds__(128, 1) void scan_kernel(
    const ushort_t* __restrict__ gx, const float* __restrict__ w_hh,
    const float* __restrict__ b_hh, uint_t* __restrict__ hbuf,
    ushort_t* __restrict__ y, float* __restrict__ h_last)
{
  __shared__ char hshb[16384];   // [b][512] bf16, 16B-chunk XOR-(b&7) swizzle

  const int m = blockIdx.x;
  const int c0 = m * 32;
  const int t = threadIdx.x;
  const int wv = t >> 6, lane = t & 63, q = lane >> 4, l16 = lane & 15;
  const int cl = (wv << 4) + l16;        // owned hcol within slice

  // ---- w_hh fragments straight into VGPRs (B-frag: n=l16 row, k=q*8 offs) ----
  bf16x8 wreg[3][16];
#pragma unroll
  for (int gi = 0; gi < 3; ++gi)
#pragma unroll
    for (int ks = 0; ks < 16; ++ks) {
      const float* src = w_hh + (size_t)(gi * 512 + c0 + cl) * 512 + ks * 32 + q * 8;
      float4 f0 = *(const float4*)src;
      float4 f1 = *(const float4*)(src + 4);
      bf16x8 wf;
      wf[0] = (short)f2bf(f0.x); wf[1] = (short)f2bf(f0.y);
      wf[2] = (short)f2bf(f0.z); wf[3] = (short)f2bf(f0.w);
      wf[4] = (short)f2bf(f1.x); wf[5] = (short)f2bf(f1.y);
      wf[6] = (short)f2bf(f1.z); wf[7] = (short)f2bf(f1.w);
      wreg[gi][ks] = wf;
    }

  const float bhr = b_hh[c0 + cl];
  const float bhz = b_hh[512 + c0 + cl];
  const float bhn = b_hh[1024 + c0 + cl];
  float hcur[4] = {0.f, 0.f, 0.f, 0.f};

  // gx for step 0 (per-lane registers)
  ushort_t gxv[3][4];
#pragma unroll
  for (int g = 0; g < 3; ++g)
#pragma unroll
    for (int r = 0; r < 4; ++r)
      gxv[g][r] = gx[(size_t)(((q << 2) + r) * S_) * GU_ + g * 512 + c0 + cl];

  // h_0 = 0
  for (int i = t; i < 4096; i += 128) ((uint_t*)hshb)[i] = 0u;

  for (int step = 0; step < S_; ++step) {
    if (step > 0) {
      // ---- poll + load h_{step} via batched bypass bursts ----
      const uint_t tg = (uint_t)step;   // slot step-1 carries tag step
      const uint_t* mb = hbuf + (size_t)(step - 1) * 8192;
      unsigned long long vals[32];
      uint_t bad;
      do {
#pragma unroll
        for (int i = 0; i < 32; ++i) {
          const uint_t* p = mb + (((i * 128) + t) << 1);
          asm volatile("global_load_dwordx2 %0, %1, off sc0 sc1"
                       : "=v"(vals[i]) : "v"(p) : "memory");
        }
        asm volatile("s_waitcnt vmcnt(0)" ::: "memory");
        bad = 0u;
#pragma unroll
        for (int i = 0; i < 32; ++i) {
          uint_t lo = (uint_t)vals[i], hi = (uint_t)(vals[i] >> 32);
          bad |= ((lo ^ tg) | (hi ^ tg)) & 0xffffu;
        }
      } while (bad != 0u);
      // ---- stage to swizzled LDS ----
#pragma unroll
      for (int i = 0; i < 32; ++i) {
        int idx2 = ((i * 128) + t) << 1;      // even dword (col) index
        int b = idx2 >> 9;
        int col0 = idx2 & 511;
        uint_t lo = (uint_t)vals[i], hi = (uint_t)(vals[i] >> 32);
        uint_t dw = (lo >> 16) | (hi & 0xffff0000u);
        *(uint_t*)(hshb + b * 1024 + ((((col0 >> 3) ^ (b & 7))) << 4) +
                   ((col0 & 7) << 1)) = dw;
      }
    }
    __syncthreads();   // LDS staging visible to both waves (lgkm drain)

    // ---- MFMA: gh tiles for this wave's 16 cols x 3 gates ----
    f32x4 acc[3] = {{0.f,0.f,0.f,0.f},{0.f,0.f,0.f,0.f},{0.f,0.f,0.f,0.f}};
#pragma unroll
    for (int ks = 0; ks < 16; ++ks) {
      bf16x8 hf = *(bf16x8*)(hshb + l16 * 1024 +
                             ((((ks << 2) + q) ^ (l16 & 7)) << 4));
#pragma unroll
      for (int gi = 0; gi < 3; ++gi)
        acc[gi] = __builtin_amdgcn_mfma_f32_16x16x32_bf16(hf, wreg[gi][ks], acc[gi], 0, 0, 0);
    }

    // ---- gates (row=batch=q*4+r, col=c0+cl) + tagged publish ----
    const uint_t tgout = (uint_t)(step + 1);
    ushort_t hb16[4];
#pragma unroll
    for (int r = 0; r < 4; ++r) {
      int b = (q << 2) + r;
      float xr  = bf2f(gxv[0][r]);
      float xz  = bf2f(gxv[1][r]);
      float xnn = bf2f(gxv[2][r]);
      float rr = 1.f / (1.f + __expf(-(xr + acc[0][r] + bhr)));
      float zz = 1.f / (1.f + __expf(-(xz + acc[1][r] + bhz)));
      float na = xnn + rr * (acc[2][r] + bhn);
      float ng = 1.f - 2.f / (1.f + __expf(2.f * na));   // tanh, inf-safe
      float hv = (1.f - zz) * ng + zz * hcur[r];
      hcur[r] = hv;
      hb16[r] = f2bf(hv);
      uint_t dw = (((uint_t)hb16[r]) << 16) | tgout;
      uint_t* pp = hbuf + (size_t)step * 8192 + b * 512 + c0 + cl;
      asm volatile("global_store_dword %0, %1, off sc0 sc1"
                   :: "v"(pp), "v"(dw) : "memory");
    }
    // ---- y (plain cached stores, drained at kernel end) ----
#pragma unroll
    for (int r = 0; r < 4; ++r)
      y[((size_t)((q << 2) + r) * S_ + step) * U_ + c0 + cl] = hb16[r];

    // ---- gx prefetch for next step (covered by the next poll window) ----
    if (step + 1 < S_) {
#pragma unroll
      for (int g = 0; g < 3; ++g)
#pragma unroll
        for (int r = 0; r < 4; ++r)
          gxv[g][r] = gx[((size_t)((q << 2) + r) * S_ + step + 1) * GU_ +
                         g * 512 + c0 + cl];
    }
  }

#pragma unroll
  for (int r = 0; r < 4; ++r)
    h_last[((q << 2) + r) * 512 + c0 + cl] = hcur[r];
}

extern "C" void kernel_launch(void* const* d_in, const int* in_sizes, int n_in,
                              void* d_out, int out_size, void* d_ws, size_t ws_size,
                              hipStream_t stream) {
  const float* x     = (const float*)d_in[0];
  const float* ln_g  = (const float*)d_in[1];
  const float* ln_b  = (const float*)d_in[2];
  const float* w_in  = (const float*)d_in[3];
  const float* b_in  = (const float*)d_in[4];
  const float* w_ih  = (const float*)d_in[5];
  const float* w_hh  = (const float*)d_in[6];
  const float* b_ih  = (const float*)d_in[7];
  const float* b_hh  = (const float*)d_in[8];
  const float* w_out = (const float*)d_in[9];
  const float* b_out = (const float*)d_in[10];

  float* out = (float*)d_out;                       // [B,S,D] fp32
  float* h_last = out + (size_t)B_ * S_ * D_;       // [B,U] fp32

  char* ws = (char*)d_ws;
  size_t off = 0;
  ushort_t* xn   = (ushort_t*)(ws + off); off += (size_t)B_ * S_ * D_ * 2;   // 32 MB
  ushort_t* u    = (ushort_t*)(ws + off); off += (size_t)B_ * S_ * U_ * 2;   // 16 MB
  ushort_t* gx   = (ushort_t*)(ws + off); off += (size_t)B_ * S_ * GU_ * 2;  // 48 MB
  ushort_t* y    = (ushort_t*)(ws + off); off += (size_t)B_ * S_ * U_ * 2;   // 16 MB
  ushort_t* winb = (ushort_t*)(ws + off); off += (size_t)U_ * D_ * 2;
  ushort_t* wihb = (ushort_t*)(ws + off); off += (size_t)GU_ * U_ * 2;
  ushort_t* woub = (ushort_t*)(ws + off); off += (size_t)D_ * U_ * 2;
  // tagged per-step h mailboxes (32 MB = S*B*U*4) alias the dead xn buffer:
  // xn is fully consumed by GEMM1 before the scan starts (same stream), and
  // stale bf16 bits / 0xAA poison cannot forge tags 1..1024.
  uint_t* hbuf = (uint_t*)xn;

  cvt_f32_bf16<<<512, 256, 0, stream>>>((const float4*)w_in,  (ushort4*)winb, U_ * D_ / 4);
  cvt_f32_bf16<<<512, 256, 0, stream>>>((const float4*)w_ih,  (ushort4*)wihb, GU_ * U_ / 4);
  cvt_f32_bf16<<<512, 256, 0, stream>>>((const float4*)w_out, (ushort4*)woub, D_ * U_ / 4);

  ln_kernel<<<B_ * S_, 256, 0, stream>>>(x, ln_g, ln_b, xn);

  // u = xn @ w_in^T + b_in  (M=16384, N=512, K=1024)
  gemm_bt<0, 1><<<dim3(B_ * S_ / 128, U_ / 128), 256, 0, stream>>>(
      xn, winb, b_in, nullptr, u, B_ * S_, U_, D_);
  // gx = u @ w_ih^T + b_ih  (M=16384, N=1536, K=512)
  gemm_bt<0, 1><<<dim3(B_ * S_ / 128, GU_ / 128), 256, 0, stream>>>(
      u, wihb, b_ih, nullptr, gx, B_ * S_, GU_, U_);

  // sequential GRU over S: 16 wgs x 128 threads, static 16 KB LDS
  scan_kernel<<<16, 128, 0, stream>>>(gx, w_hh, b_hh, hbuf, y, h_last);

  // out = x + y @ w_out^T + b_out  (M=16384, N=1024, K=512)
  gemm_bt<1, 0><<<dim3(B_ * S_ / 128, D_ / 128), 256, 0, stream>>>(
      y, woub, b_out, x, out, B_ * S_, D_, U_);
}

// Round 5
// 3082.684 us; speedup vs baseline: 2.7560x; 1.3255x over previous
//
#include <hip/hip_runtime.h>

typedef unsigned short ushort_t;
typedef unsigned int uint_t;
typedef __attribute__((ext_vector_type(8))) short bf16x8;
typedef __attribute__((ext_vector_type(4))) float f32x4;
typedef __attribute__((ext_vector_type(4))) unsigned int uintx4;

#define B_  16
#define S_  1024
#define D_  1024
#define U_  512
#define GU_ 1536  // 3*U

// ---------- bf16 helpers (RNE) ----------
__device__ __forceinline__ ushort_t f2bf(float f) {
  union { float f; uint_t u; } v; v.f = f;
  uint_t r = v.u + 0x7fffu + ((v.u >> 16) & 1u);
  return (ushort_t)(r >> 16);
}
__device__ __forceinline__ float bf2f(ushort_t b) {
  union { uint_t u; float f; } v; v.u = ((uint_t)b) << 16; return v.f;
}

// ---------- fp32 -> bf16 weight conversion ----------
__global__ void cvt_f32_bf16(const float4* __restrict__ in, ushort4* __restrict__ out, int n4) {
  int i = blockIdx.x * blockDim.x + threadIdx.x;
  int stride = gridDim.x * blockDim.x;
  for (; i < n4; i += stride) {
    float4 f = in[i];
    ushort4 o; o.x = f2bf(f.x); o.y = f2bf(f.y); o.z = f2bf(f.z); o.w = f2bf(f.w);
    out[i] = o;
  }
}

// ---------- LayerNorm: x fp32 [BS, 1024] -> xn bf16 ----------
__global__ __launch_bounds__(256) void ln_kernel(
    const float* __restrict__ x, const float* __restrict__ gamma,
    const float* __restrict__ beta, ushort_t* __restrict__ xn)
{
  int row = blockIdx.x;
  int t = threadIdx.x;
  const float* xr = x + (size_t)row * 1024;
  float4 v = *(const float4*)(xr + t * 4);
  float s = v.x + v.y + v.z + v.w;
  float ss = v.x * v.x + v.y * v.y + v.z * v.z + v.w * v.w;
#pragma unroll
  for (int o = 32; o > 0; o >>= 1) {
    s  += __shfl_down(s, o, 64);
    ss += __shfl_down(ss, o, 64);
  }
  __shared__ float red[2][4];
  __shared__ float mv[2];
  int wv = t >> 6, ln = t & 63;
  if (ln == 0) { red[0][wv] = s; red[1][wv] = ss; }
  __syncthreads();
  if (t == 0) {
    float S1 = red[0][0] + red[0][1] + red[0][2] + red[0][3];
    float S2 = red[1][0] + red[1][1] + red[1][2] + red[1][3];
    float mu = S1 * (1.f / 1024.f);
    float var = S2 * (1.f / 1024.f) - mu * mu;
    mv[0] = mu;
    mv[1] = rsqrtf(var + 1e-5f);
  }
  __syncthreads();
  float mu = mv[0], rs = mv[1];
  float4 gm = *(const float4*)(gamma + t * 4);
  float4 bt = *(const float4*)(beta + t * 4);
  ushort4 o;
  o.x = f2bf((v.x - mu) * rs * gm.x + bt.x);
  o.y = f2bf((v.y - mu) * rs * gm.y + bt.y);
  o.z = f2bf((v.z - mu) * rs * gm.z + bt.z);
  o.w = f2bf((v.w - mu) * rs * gm.w + bt.w);
  *(ushort4*)(xn + (size_t)row * 1024 + t * 4) = o;
}

// ---------- GEMM: C[M,N] = A[M,K](bf16) @ Bw[N,K](bf16)^T + bias (+resid) ----------
template<int RES, int OBF>
__global__ __launch_bounds__(256, 2) void gemm_bt(
    const ushort_t* __restrict__ A, const ushort_t* __restrict__ Bw,
    const float* __restrict__ bias, const float* __restrict__ resid,
    void* __restrict__ Cout, int M, int N, int K)
{
  __shared__ ushort_t As[128][40];
  __shared__ ushort_t Bs[128][40];
  int bm = blockIdx.x, bn = blockIdx.y;
  int tid = threadIdx.x;
  int wave = tid >> 6, lane = tid & 63;
  int wm = wave >> 1, wn = wave & 1;
  int q = lane >> 4, l16 = lane & 15;
  f32x4 acc[4][4];
#pragma unroll
  for (int i = 0; i < 4; i++)
#pragma unroll
    for (int j = 0; j < 4; j++) acc[i][j] = (f32x4){0.f, 0.f, 0.f, 0.f};
  int r0 = tid >> 2, kc = tid & 3;
  const int nk = K >> 5;
  for (int it = 0; it < nk; ++it) {
#pragma unroll
    for (int h = 0; h < 2; ++h) {
      int r = r0 + h * 64;
      const uint4* pa = (const uint4*)(A + (size_t)(bm * 128 + r) * K + it * 32 + kc * 8);
      *(uint4*)&As[r][kc * 8] = *pa;
      const uint4* pb = (const uint4*)(Bw + (size_t)(bn * 128 + r) * K + it * 32 + kc * 8);
      *(uint4*)&Bs[r][kc * 8] = *pb;
    }
    __syncthreads();
    bf16x8 af[4], bfr[4];
#pragma unroll
    for (int i = 0; i < 4; i++) af[i]  = *(bf16x8*)&As[wm * 64 + i * 16 + l16][q * 8];
#pragma unroll
    for (int j = 0; j < 4; j++) bfr[j] = *(bf16x8*)&Bs[wn * 64 + j * 16 + l16][q * 8];
#pragma unroll
    for (int i = 0; i < 4; i++)
#pragma unroll
      for (int j = 0; j < 4; j++)
        acc[i][j] = __builtin_amdgcn_mfma_f32_16x16x32_bf16(af[i], bfr[j], acc[i][j], 0, 0, 0);
    __syncthreads();
  }
#pragma unroll
  for (int i = 0; i < 4; i++) {
#pragma unroll
    for (int j = 0; j < 4; j++) {
      int n = bn * 128 + wn * 64 + j * 16 + l16;
      float bv = bias[n];
#pragma unroll
      for (int rr = 0; rr < 4; rr++) {
        int m = bm * 128 + wm * 64 + i * 16 + q * 4 + rr;
        float v = acc[i][j][rr] + bv;
        if (RES) v += resid[(size_t)m * N + n];
        if (OBF) ((ushort_t*)Cout)[(size_t)m * N + n] = f2bf(v);
        else     ((float*)Cout)[(size_t)m * N + n] = v;
      }
    }
  }
}

// ---------- GRU scan (16 wgs, release-protocol mailbox) ----------
// wg m owns h-cols [32m,32m+32) for all 16 batches. Per step, publish:
//   data stores (2 bf16 cols/dword, sc0 sc1) -> __syncthreads (vmcnt(0) drain
//   for BOTH waves) -> one tag dword mtag[slot][m] = step+1 (sc0 sc1).
// Reader: poll the 64B tag line (1 load/iter) until all 16 == step, then read
// the 16KB data slot exactly ONCE. 2-slot ping-pong safe: a wg's tag for step
// s is its receipt that it finished consuming slot s-1 (publish follows data
// read in program order), and slot parity p is only overwritten at step p+2,
// which requires all 16 tags of step p+1.
__global__ __launch_bounds__(128, 1) void scan_kernel(
    const ushort_t* __restrict__ gx, const float* __restrict__ w_hh,
    const float* __restrict__ b_hh, uint_t* __restrict__ mdata,
    uint_t* __restrict__ mtag, ushort_t* __restrict__ y,
    float* __restrict__ h_last)
{
  extern __shared__ char smem[];
  ushort_t* wlds = (ushort_t*)smem;   // 48 KB: [gi*16+wv*8+ks][lane][8] B-frags, ks 0..7
  char* hshb = smem + 49152;          // 16 KB: [b][512] bf16, 16B-chunk XOR-(b&7) swizzle

  const int m = blockIdx.x;
  const int c0 = m * 32;
  const int t = threadIdx.x;
  const int wv = t >> 6, lane = t & 63, q = lane >> 4, l16 = lane & 15;
  const int cl = (wv << 4) + l16;      // owned hcol within slice, 0..31

  // ---- w_hh ks=0..7 fragments into LDS (both waves' col-halves) ----
  for (int idx = t; idx < 48 * 64; idx += 128) {
    int cc = idx >> 6, ln = idx & 63;
    int gi = cc >> 4, wv2 = (cc >> 3) & 1, ks = cc & 7;
    int n = c0 + (wv2 << 4) + (ln & 15);
    int k0 = (ks << 5) + ((ln >> 4) << 3);
    const float* src = w_hh + (size_t)(gi * 512 + n) * 512 + k0;
    float4 f0 = *(const float4*)src;
    float4 f1 = *(const float4*)(src + 4);
    uint4 pk;
    pk.x = (uint_t)f2bf(f0.x) | ((uint_t)f2bf(f0.y) << 16);
    pk.y = (uint_t)f2bf(f0.z) | ((uint_t)f2bf(f0.w) << 16);
    pk.z = (uint_t)f2bf(f1.x) | ((uint_t)f2bf(f1.y) << 16);
    pk.w = (uint_t)f2bf(f1.z) | ((uint_t)f2bf(f1.w) << 16);
    *(uint4*)(wlds + (size_t)cc * 512 + ln * 8) = pk;
  }
  // ---- w_hh ks=8..15 fragments in VGPRs (96 regs) ----
  bf16x8 wreg[3][8];
#pragma unroll
  for (int gi = 0; gi < 3; ++gi)
#pragma unroll
    for (int k8 = 0; k8 < 8; ++k8) {
      const float* src = w_hh + (size_t)(gi * 512 + c0 + cl) * 512 + (8 + k8) * 32 + q * 8;
      float4 f0 = *(const float4*)src;
      float4 f1 = *(const float4*)(src + 4);
      bf16x8 wf;
      wf[0] = (short)f2bf(f0.x); wf[1] = (short)f2bf(f0.y);
      wf[2] = (short)f2bf(f0.z); wf[3] = (short)f2bf(f0.w);
      wf[4] = (short)f2bf(f1.x); wf[5] = (short)f2bf(f1.y);
      wf[6] = (short)f2bf(f1.z); wf[7] = (short)f2bf(f1.w);
      wreg[gi][k8] = wf;
    }

  const float bhr = b_hh[c0 + cl];
  const float bhz = b_hh[512 + c0 + cl];
  const float bhn = b_hh[1024 + c0 + cl];
  float hcur[4] = {0.f, 0.f, 0.f, 0.f};

  // gx for step 0
  ushort_t gxv[3][4];
#pragma unroll
  for (int g = 0; g < 3; ++g)
#pragma unroll
    for (int r = 0; r < 4; ++r)
      gxv[g][r] = gx[(size_t)(((q << 2) + r) * S_) * GU_ + g * 512 + c0 + cl];

  // h_0 = 0
  for (int i = t; i < 4096; i += 128) ((uint_t*)hshb)[i] = 0u;

  const int l64 = t & 63;
  for (int step = 0; step < S_; ++step) {
    if (step > 0) {
      const uint_t want = (uint_t)step;       // publishers of step-1 wrote tag step
      const int slot = (step - 1) & 1;
      // ---- poll the 16-tag line (one dword per lane, broadcast line) ----
      const uint_t* tp = mtag + slot * 16 + (lane & 15);
      uint_t tv;
      do {
        asm volatile("global_load_dword %0, %1, off sc0 sc1"
                     : "=v"(tv) : "v"(tp) : "memory");
        asm volatile("s_waitcnt vmcnt(0)" ::: "memory");
      } while (!__all((int)(tv == want)));
      // ---- single data read: 8 x dwordx4 per thread covers the 16 KB slot ----
      const uint_t* db = mdata + slot * 4096;
      uintx4 vals[8];
#pragma unroll
      for (int j = 0; j < 8; ++j) {
        const uint_t* p = db + j * 512 + t * 4;
        asm volatile("global_load_dwordx4 %0, %1, off sc0 sc1"
                     : "=v"(vals[j]) : "v"(p) : "memory");
      }
      asm volatile("s_waitcnt vmcnt(0)" ::: "memory");
      // ---- stage: thread t burst j = batch 2j+wv, cols [8*l64, 8*l64+8) ----
#pragma unroll
      for (int j = 0; j < 8; ++j) {
        int b = 2 * j + wv;
        *(uint4*)(hshb + b * 1024 + ((l64 ^ (b & 7)) << 4)) = *(uint4*)&vals[j];
      }
    }
    __syncthreads();

    // ---- MFMA: gh tiles (rows=batch, cols=this wave's 16 hcols x 3 gates) ----
    f32x4 acc[3] = {{0.f,0.f,0.f,0.f},{0.f,0.f,0.f,0.f},{0.f,0.f,0.f,0.f}};
#pragma unroll
    for (int ks = 0; ks < 16; ++ks) {
      bf16x8 hf = *(bf16x8*)(hshb + l16 * 1024 +
                             ((((ks << 2) + q) ^ (l16 & 7)) << 4));
#pragma unroll
      for (int gi = 0; gi < 3; ++gi) {
        bf16x8 wf;
        if (ks < 8) wf = *(bf16x8*)(wlds + (size_t)((gi * 2 + wv) * 8 + ks) * 512 + lane * 8);
        else        wf = wreg[gi][ks - 8];
        acc[gi] = __builtin_amdgcn_mfma_f32_16x16x32_bf16(hf, wf, acc[gi], 0, 0, 0);
      }
    }

    // ---- gates (row=batch=q*4+r, col=c0+cl) ----
    ushort_t hb16[4];
#pragma unroll
    for (int r = 0; r < 4; ++r) {
      float xr  = bf2f(gxv[0][r]);
      float xz  = bf2f(gxv[1][r]);
      float xnn = bf2f(gxv[2][r]);
      float rr = 1.f / (1.f + __expf(-(xr + acc[0][r] + bhr)));
      float zz = 1.f / (1.f + __expf(-(xz + acc[1][r] + bhz)));
      float na = xnn + rr * (acc[2][r] + bhn);
      float ng = 1.f - 2.f / (1.f + __expf(2.f * na));   // tanh, inf-safe
      float hv = (1.f - zz) * ng + zz * hcur[r];
      hcur[r] = hv;
      hb16[r] = f2bf(hv);
    }

    // ---- publish (skip at last step: nobody polls it) ----
    if (step < S_ - 1) {
      const int oslot = step & 1;
#pragma unroll
      for (int r = 0; r < 4; ++r) {
        uint_t other = (uint_t)__shfl_xor((int)(uint_t)hb16[r], 1, 64);
        if ((lane & 1) == 0) {
          uint_t dw = ((uint_t)hb16[r]) | (other << 16);   // even col lo, odd hi
          int b = (q << 2) + r;
          uint_t* pp = mdata + oslot * 4096 + b * 256 + ((c0 + cl) >> 1);
          asm volatile("global_store_dword %0, %1, off sc0 sc1"
                       :: "v"(pp), "v"(dw) : "memory");
        }
      }
      __syncthreads();   // built-in vmcnt(0): BOTH waves' data stores drained
      if (t == 0) {
        uint_t tagv = (uint_t)(step + 1);
        uint_t* tp = mtag + oslot * 16 + m;
        asm volatile("global_store_dword %0, %1, off sc0 sc1"
                     :: "v"(tp), "v"(tagv) : "memory");
      }
    }

    // ---- y stores (plain cached; drained at kernel end) ----
#pragma unroll
    for (int r = 0; r < 4; ++r)
      y[((size_t)((q << 2) + r) * S_ + step) * U_ + c0 + cl] = hb16[r];

    // ---- gx prefetch for next step (in flight across the next poll) ----
    if (step + 1 < S_) {
#pragma unroll
      for (int g = 0; g < 3; ++g)
#pragma unroll
        for (int r = 0; r < 4; ++r)
          gxv[g][r] = gx[((size_t)((q << 2) + r) * S_ + step + 1) * GU_ +
                         g * 512 + c0 + cl];
    }
  }

#pragma unroll
  for (int r = 0; r < 4; ++r)
    h_last[((q << 2) + r) * 512 + c0 + cl] = hcur[r];
}

extern "C" void kernel_launch(void* const* d_in, const int* in_sizes, int n_in,
                              void* d_out, int out_size, void* d_ws, size_t ws_size,
                              hipStream_t stream) {
  const float* x     = (const float*)d_in[0];
  const float* ln_g  = (const float*)d_in[1];
  const float* ln_b  = (const float*)d_in[2];
  const float* w_in  = (const float*)d_in[3];
  const float* b_in  = (const float*)d_in[4];
  const float* w_ih  = (const float*)d_in[5];
  const float* w_hh  = (const float*)d_in[6];
  const float* b_ih  = (const float*)d_in[7];
  const float* b_hh  = (const float*)d_in[8];
  const float* w_out = (const float*)d_in[9];
  const float* b_out = (const float*)d_in[10];

  float* out = (float*)d_out;                       // [B,S,D] fp32
  float* h_last = out + (size_t)B_ * S_ * D_;       // [B,U] fp32

  char* ws = (char*)d_ws;
  size_t off = 0;
  ushort_t* xn   = (ushort_t*)(ws + off); off += (size_t)B_ * S_ * D_ * 2;   // 32 MB
  ushort_t* u    = (ushort_t*)(ws + off); off += (size_t)B_ * S_ * U_ * 2;   // 16 MB
  ushort_t* gx   = (ushort_t*)(ws + off); off += (size_t)B_ * S_ * GU_ * 2;  // 48 MB
  ushort_t* y    = (ushort_t*)(ws + off); off += (size_t)B_ * S_ * U_ * 2;   // 16 MB
  ushort_t* winb = (ushort_t*)(ws + off); off += (size_t)U_ * D_ * 2;
  ushort_t* wihb = (ushort_t*)(ws + off); off += (size_t)GU_ * U_ * 2;
  ushort_t* woub = (ushort_t*)(ws + off); off += (size_t)D_ * U_ * 2;
  uint_t* mtag   = (uint_t*)(ws + off);   off += 256;          // 2 slots x 16 tags
  // data mailbox (2 slots x 16 KB) aliases the dead xn buffer: xn's last use
  // is GEMM1 (stream-ordered before the scan); data is only read after a tag
  // validates, and tags live in fresh ws (poison 0xAAAAAAAA can't forge 1..1024).
  uint_t* mdata  = (uint_t*)xn;

  cvt_f32_bf16<<<512, 256, 0, stream>>>((const float4*)w_in,  (ushort4*)winb, U_ * D_ / 4);
  cvt_f32_bf16<<<512, 256, 0, stream>>>((const float4*)w_ih,  (ushort4*)wihb, GU_ * U_ / 4);
  cvt_f32_bf16<<<512, 256, 0, stream>>>((const float4*)w_out, (ushort4*)woub, D_ * U_ / 4);

  ln_kernel<<<B_ * S_, 256, 0, stream>>>(x, ln_g, ln_b, xn);

  // u = xn @ w_in^T + b_in  (M=16384, N=512, K=1024)
  gemm_bt<0, 1><<<dim3(B_ * S_ / 128, U_ / 128), 256, 0, stream>>>(
      xn, winb, b_in, nullptr, u, B_ * S_, U_, D_);
  // gx = u @ w_ih^T + b_ih  (M=16384, N=1536, K=512)
  gemm_bt<0, 1><<<dim3(B_ * S_ / 128, GU_ / 128), 256, 0, stream>>>(
      u, wihb, b_ih, nullptr, gx, B_ * S_, GU_, U_);

  // belt-and-braces: zero the tag lines (0 and 0xAAAAAAAA are both non-tags)
  hipMemsetAsync(mtag, 0, 256, stream);

  // sequential GRU: 16 wgs x 128 threads, 64 KB pure-dynamic LDS (R2-proven)
  (void)hipFuncSetAttribute(reinterpret_cast<const void*>(scan_kernel),
                            hipFuncAttributeMaxDynamicSharedMemorySize, 65536);
  scan_kernel<<<16, 128, 65536, stream>>>(gx, w_hh, b_hh, mdata, mtag, y, h_last);

  // out = x + y @ w_out^T + b_out  (M=16384, N=1024, K=512)
  gemm_bt<1, 0><<<dim3(B_ * S_ / 128, D_ / 128), 256, 0, stream>>>(
      y, woub, b_out, x, out, B_ * S_, D_, U_);
}